// Round 14
// baseline (3914.966 us; speedup 1.0000x reference)
//
#include <hip/hip_runtime.h>

// PointNet Set Abstraction (B=16, N=4096, S=1024, K=32, D=64, mlp 67->64->64->128)
// All buffers float32. Exact fp32 (RN, numpy op order) for all DECISIONS.
//
// R14 = R13 with the producer's post-barrier chain shortened: the wave-winner
// lane publishes its centroid COORDS next to the wave's key before the barrier
// (unique lane: pre-reduce key == readlane(key,63); coords via cndmask select
// on its tracked p). Post-barrier: ONE LDS RT loads 8 keys + 8 coord quads;
// tree on keys -> idx -> wave-index cndmask select of coords. Removes the
// dependent lx/ly/lz[idx] second RT (~120-140 cyc/iter).
// Keys/tree/decision math byte-identical. Consumer byte-identical to R13.

typedef unsigned int   u32;
typedef unsigned long long u64;

#define NB 16
#define NP 4096
#define NS 1024
#define NK 32
#define NITEM (NB * NS / 2)   // 8192 pair items

#define DPP_UPD(v, ctrl) ((u32)__builtin_amdgcn_update_dpp((int)(v), (int)(v), (ctrl), 0xf, 0xf, false))
#define U64_STEP(v, ctrl) { \
  u32 _lo = DPP_UPD((u32)(v), ctrl); \
  u32 _hi = DPP_UPD((u32)((v) >> 32), ctrl); \
  u64 _o = (((u64)_hi) << 32) | _lo; \
  v = (v > _o) ? v : _o; }
#define WAVE_RED_U64MAX(v) do { U64_STEP(v,0x111); U64_STEP(v,0x112); U64_STEP(v,0x114); \
                                U64_STEP(v,0x118); U64_STEP(v,0x142); U64_STEP(v,0x143); } while (0)
#define UMAX_DPP(v, ctrl) { u32 _o = DPP_UPD(v, ctrl); v = (v > _o) ? v : _o; }
#define HALF_RED_UMAX32(v) do { UMAX_DPP(v,0x111); UMAX_DPP(v,0x112); UMAX_DPP(v,0x114); \
                                UMAX_DPP(v,0x118); UMAX_DPP(v,0x142); } while (0)

struct FpsS { float lx[NP], ly[NP], lz[NP]; u64 red[2][8]; float4 cs[2][8]; };
struct HalfS {
  float x0[64 * 67];
  u64 masks[2][64];
  int offs[2][64];
  int idx_ls[2][NK];
  float cent[8];
};
struct ConS { HalfS h[2]; float sAB[512]; int shi; };
union SMem { FpsS f; ConS c; };

__device__ __forceinline__ float dload_f(const float* p) {
  return __uint_as_float(__hip_atomic_load((const u32*)p, __ATOMIC_RELAXED, __HIP_MEMORY_SCOPE_AGENT));
}

__global__ void __launch_bounds__(512)
fused_kernel(const float* __restrict__ xyz, const float* __restrict__ pts,
             const float* __restrict__ W0, const float* __restrict__ b0, const float* __restrict__ g0,
             const float* __restrict__ be0, const float* __restrict__ m0, const float* __restrict__ v0,
             const float* __restrict__ W1, const float* __restrict__ b1, const float* __restrict__ g1,
             const float* __restrict__ be1, const float* __restrict__ m1, const float* __restrict__ v1,
             const float* __restrict__ W2, const float* __restrict__ b2, const float* __restrict__ g2,
             const float* __restrict__ be2, const float* __restrict__ m2, const float* __restrict__ v2,
             float* __restrict__ out0, float* __restrict__ out1,
             int* __restrict__ progress, int* __restrict__ ctr)
{
  __shared__ SMem sm;
  const int t = threadIdx.x;

  if (blockIdx.x < NB) {
    // ================= FPS producer =================
    asm volatile("s_setprio 3");
    FpsS& S = sm.f;
    const int b = blockIdx.x;
    const int lane = t & 63, wv = t >> 6;
    const float* bx = xyz + (size_t)b * NP * 3;
    for (int i = t; i < NP; i += 512) {
      S.lx[i] = bx[i * 3 + 0];
      S.ly[i] = bx[i * 3 + 1];
      S.lz[i] = bx[i * 3 + 2];
    }
    __syncthreads();

    float px[8], py[8], pz[8], md[8];
#pragma unroll
    for (int p = 0; p < 8; ++p) {
      int i = p * 512 + t;
      px[p] = S.lx[i]; py[p] = S.ly[i]; pz[p] = S.lz[i];
      md[p] = 1e10f;
    }
    const u32 nt = ~(u32)t;
    float cx = S.lx[0], cy = S.ly[0], cz = S.lz[0];
    float hx = cx, hy = cy, hz = cz;   // lane 0's capture slot = centroid 0 (seed)

    for (int it = 1; it < NS; ++it) {
      u32 vb, ca;
      {
        float dx = __fsub_rn(px[0], cx);
        float dy = __fsub_rn(py[0], cy);
        float dz = __fsub_rn(pz[0], cz);
        float d  = __fadd_rn(__fadd_rn(__fmul_rn(dx, dx), __fmul_rn(dy, dy)), __fmul_rn(dz, dz));
        float m2 = fminf(md[0], d);
        md[0] = m2;
        vb = __float_as_uint(m2);
        ca = nt;
      }
#pragma unroll
      for (int p = 1; p < 8; ++p) {
        float dx = __fsub_rn(px[p], cx);
        float dy = __fsub_rn(py[p], cy);
        float dz = __fsub_rn(pz[p], cz);
        float d  = __fadd_rn(__fadd_rn(__fmul_rn(dx, dx), __fmul_rn(dy, dy)), __fmul_rn(dz, dz));
        float m2 = fminf(md[p], d);
        md[p] = m2;
        u32 mb = __float_as_uint(m2);
        bool gt = mb > vb;                      // strict > keeps first idx on ties
        vb = gt ? mb : vb;
        ca = gt ? (nt - (u32)(p * 512)) : ca;   // ~(p*512+t)
      }
      u64 key = (((u64)vb) << 32) | ca;
      const u64 okey = key;                     // pre-reduce copy (unique per lane)
      WAVE_RED_U64MAX(key);
      const int par = it & 1;
      // this wave's max key (broadcast from lane 63)
      const u64 wkey = (((u64)(u32)__builtin_amdgcn_readlane((int)(key >> 32), 63)) << 32)
                       | (u32)__builtin_amdgcn_readlane((int)key, 63);
      if (lane == 63) S.red[par][wv] = key;
      if (okey == wkey) {                       // unique winner lane of this wave
        int ix = (int)(~(u32)okey);             // winning global point index
        int p = ix >> 9;                        // its slot in my registers
        float sx = (p & 4) ? ((p & 2) ? ((p & 1) ? px[7] : px[6]) : ((p & 1) ? px[5] : px[4]))
                           : ((p & 2) ? ((p & 1) ? px[3] : px[2]) : ((p & 1) ? px[1] : px[0]));
        float sy = (p & 4) ? ((p & 2) ? ((p & 1) ? py[7] : py[6]) : ((p & 1) ? py[5] : py[4]))
                           : ((p & 2) ? ((p & 1) ? py[3] : py[2]) : ((p & 1) ? py[1] : py[0]));
        float sz = (p & 4) ? ((p & 2) ? ((p & 1) ? pz[7] : pz[6]) : ((p & 1) ? pz[5] : pz[4]))
                           : ((p & 2) ? ((p & 1) ? pz[3] : pz[2]) : ((p & 1) ? pz[1] : pz[0]));
        S.cs[par][wv] = make_float4(sx, sy, sz, 0.0f);
      }
      __syncthreads();
      u64 k0 = S.red[par][0], k1 = S.red[par][1], k2 = S.red[par][2], k3 = S.red[par][3];
      u64 k4 = S.red[par][4], k5 = S.red[par][5], k6 = S.red[par][6], k7 = S.red[par][7];
      float4 c0 = S.cs[par][0], c1 = S.cs[par][1], c2 = S.cs[par][2], c3 = S.cs[par][3];
      float4 c4 = S.cs[par][4], c5 = S.cs[par][5], c6 = S.cs[par][6], c7 = S.cs[par][7];
      u64 m01 = (k0 > k1) ? k0 : k1;
      u64 m23 = (k2 > k3) ? k2 : k3;
      u64 m45 = (k4 > k5) ? k4 : k5;
      u64 m67 = (k6 > k7) ? k6 : k7;
      u64 ma = (m01 > m23) ? m01 : m23;
      u64 mb = (m45 > m67) ? m45 : m67;
      u64 bk = (ma > mb) ? ma : mb;
      const int idx = (int)(~(u32)bk);
      const int ww = (idx & 511) >> 6;          // winning wave -> coord slot
      float4 cw = (ww & 4) ? ((ww & 2) ? ((ww & 1) ? c7 : c6) : ((ww & 1) ? c5 : c4))
                           : ((ww & 2) ? ((ww & 1) ? c3 : c2) : ((ww & 1) ? c1 : c0));
      cx = cw.x; cy = cw.y; cz = cw.z;
      if (wv == 0) {
        // lane (it&15) captures this iteration's centroid
        bool cap = (lane == (it & 15));
        hx = cap ? cx : hx;
        hy = cap ? cy : hy;
        hz = cap ? cz : hz;
        if ((it & 15) == 15) {
          if (lane < 16) {                       // burst cents (it-15)..it, 192B coalesced
            float* o = out0 + ((size_t)b * NS + (it - 15) + lane) * 3;
            o[0] = hx; o[1] = hy; o[2] = hz;
          }
          if (lane == 0)                         // release fences the burst agent-wide
            __hip_atomic_store(&progress[b * 16], it + 1, __ATOMIC_RELEASE, __HIP_MEMORY_SCOPE_AGENT);
        }
      }
    }
    return;
  }

  // ================= consumer (byte-identical to R13) =================
  ConS& C = sm.c;
  const int half = t >> 8;
  const int u = t & 255;
  const int lane = t & 63;
  const int hw = u >> 6;
  HalfS& H = C.h[half];
  const float R2 = (float)(0.2 * 0.2);

  if (t < 256) {
    const float *gp, *bep, *mp, *vp, *bpp; int c, base, bcoff;
    if (t < 64)       { c = t;       gp = g0; bep = be0; mp = m0; vp = v0; bpp = b0; base = 0;   bcoff = 64;  }
    else if (t < 128) { c = t - 64;  gp = g1; bep = be1; mp = m1; vp = v1; bpp = b1; base = 128; bcoff = 64;  }
    else              { c = t - 128; gp = g2; bep = be2; mp = m2; vp = v2; bpp = b2; base = 256; bcoff = 128; }
    float a = gp[c] / sqrtf(vp[c] + 1e-5f);
    C.sAB[base + c] = a;
    C.sAB[base + bcoff + c] = (bpp[c] - mp[c]) * a + bep[c];
  }
  __syncthreads();

  for (;;) {
    if (t == 0) C.shi = atomicAdd(ctr, 2);
    __syncthreads();
    const int i0 = C.shi;
    if (i0 >= NITEM) break;
    const int item = i0 + half;
    const bool active = item < NITEM;
    const int b = item & 15, pr = item >> 4, s0 = pr * 2;

    if (u == 0 && active) {
      const int need = s0 + 2;
      while (__hip_atomic_load(&progress[b * 16], __ATOMIC_ACQUIRE, __HIP_MEMORY_SCOPE_AGENT) < need)
        __builtin_amdgcn_s_sleep(32);
      const float* cp = out0 + ((size_t)b * NS + s0) * 3;
#pragma unroll
      for (int i2 = 0; i2 < 6; ++i2) H.cent[i2] = dload_f(cp + i2);
    }
    __syncthreads();
    const float c0x = H.cent[0], c0y = H.cent[1], c0z = H.cent[2];
    const float c1x = H.cent[3], c1y = H.cent[4], c1z = H.cent[5];
    const float* bx = xyz + (size_t)b * NP * 3;

    if (active) {
      for (int c = 0; c < 16; ++c) {
        int ch = hw * 16 + c;
        int i = ch * 64 + lane;
        float X = bx[i * 3 + 0], Y = bx[i * 3 + 1], Z = bx[i * 3 + 2];
        float dx0 = __fsub_rn(c0x, X), dy0 = __fsub_rn(c0y, Y), dz0 = __fsub_rn(c0z, Z);
        float d20 = __fadd_rn(__fadd_rn(__fmul_rn(dx0, dx0), __fmul_rn(dy0, dy0)), __fmul_rn(dz0, dz0));
        u64 mA = __ballot(d20 < R2);
        float dx1 = __fsub_rn(c1x, X), dy1 = __fsub_rn(c1y, Y), dz1 = __fsub_rn(c1z, Z);
        float d21 = __fadd_rn(__fadd_rn(__fmul_rn(dx1, dx1), __fmul_rn(dy1, dy1)), __fmul_rn(dz1, dz1));
        u64 mB = __ballot(d21 < R2);
        if (lane == 0) { H.masks[0][ch] = mA; H.masks[1][ch] = mB; }
      }
      if (u < 64) H.idx_ls[u >> 5][u & 31] = -1;
    }
    __syncthreads();
    if (active && (hw & 1) == 0) {
      int cent = hw >> 1;
      int cnt = __popcll(H.masks[cent][lane]);
      int inc = cnt;
#pragma unroll
      for (int off = 1; off < 64; off <<= 1) {
        int n = __shfl_up(inc, off);
        if (lane >= off) inc += n;
      }
      H.offs[cent][lane] = inc - cnt;
    }
    __syncthreads();
    if (active) {
      for (int c = 0; c < 16; ++c) {
        int ch = hw * 16 + c;
#pragma unroll
        for (int cent = 0; cent < 2; ++cent) {
          int base = H.offs[cent][ch];
          if (base >= NK) continue;
          u64 m = H.masks[cent][ch];
          if ((m >> lane) & 1ull) {
            int slot = base + __popcll(m & ((1ull << lane) - 1ull));
            if (slot < NK) H.idx_ls[cent][slot] = ch * 64 + lane;
          }
        }
      }
    }
    __syncthreads();
    if (active) {
      int cent = u >> 7, tt = u & 127;
      int row = tt >> 2, q = tt & 3;
      int id = H.idx_ls[cent][row];
      int prow = (id < 0) ? (NP - 1) : id;          // torch -1 wrap
      const float4* p4 = (const float4*)(pts + ((size_t)b * NP + prow) * 64 + q * 16);
      float4 va = p4[0], vb = p4[1], vc = p4[2], vd = p4[3];
      float* dst = &H.x0[(cent * 32 + row) * 67 + 3 + q * 16];
      dst[0]  = va.x; dst[1]  = va.y; dst[2]  = va.z; dst[3]  = va.w;
      dst[4]  = vb.x; dst[5]  = vb.y; dst[6]  = vb.z; dst[7]  = vb.w;
      dst[8]  = vc.x; dst[9]  = vc.y; dst[10] = vc.z; dst[11] = vc.w;
      dst[12] = vd.x; dst[13] = vd.y; dst[14] = vd.z; dst[15] = vd.w;
      if (u < 64) {
        int c2 = u >> 5, slot = u & 31;
        int id2 = H.idx_ls[c2][slot];
        float ax = c2 ? c1x : c0x, ay = c2 ? c1y : c0y, az = c2 ? c1z : c0z;
        float gx, gy, gz;
        if (id2 >= 0) {
          gx = __fsub_rn(bx[id2 * 3 + 0], ax);
          gy = __fsub_rn(bx[id2 * 3 + 1], ay);
          gz = __fsub_rn(bx[id2 * 3 + 2], az);
        } else {
          gx = 0.0f - ax; gy = 0.0f - ay; gz = 0.0f - az;
        }
        float* d2p = &H.x0[(c2 * 32 + slot) * 67];
        d2p[0] = gx; d2p[1] = gy; d2p[2] = gz;
      }
    }
    __syncthreads();

    const int j0 = __builtin_amdgcn_readfirstlane(hw * 16);
    // --- layer 1: 67 -> 64 (in-place)
    {
      float acc[16];
#pragma unroll
      for (int i = 0; i < 16; ++i) acc[i] = 0.0f;
      if (active) {
        const float* xr = &H.x0[lane * 67];
#pragma unroll 2
        for (int c = 0; c < 67; ++c) {
          float xv = xr[c];
          const float4* wr = (const float4*)(W0 + c * 64 + j0);
          float4 wa = wr[0], wb = wr[1], wc = wr[2], wd = wr[3];
          acc[0]  = fmaf(xv, wa.x, acc[0]);  acc[1]  = fmaf(xv, wa.y, acc[1]);
          acc[2]  = fmaf(xv, wa.z, acc[2]);  acc[3]  = fmaf(xv, wa.w, acc[3]);
          acc[4]  = fmaf(xv, wb.x, acc[4]);  acc[5]  = fmaf(xv, wb.y, acc[5]);
          acc[6]  = fmaf(xv, wb.z, acc[6]);  acc[7]  = fmaf(xv, wb.w, acc[7]);
          acc[8]  = fmaf(xv, wc.x, acc[8]);  acc[9]  = fmaf(xv, wc.y, acc[9]);
          acc[10] = fmaf(xv, wc.z, acc[10]); acc[11] = fmaf(xv, wc.w, acc[11]);
          acc[12] = fmaf(xv, wd.x, acc[12]); acc[13] = fmaf(xv, wd.y, acc[13]);
          acc[14] = fmaf(xv, wd.z, acc[14]); acc[15] = fmaf(xv, wd.w, acc[15]);
        }
      }
      __syncthreads();
      if (active) {
#pragma unroll
        for (int i = 0; i < 16; ++i) {
          float y = fmaf(acc[i], C.sAB[j0 + i], C.sAB[64 + j0 + i]);
          H.x0[lane * 67 + j0 + i] = fmaxf(y, 0.0f);
        }
      }
    }
    __syncthreads();
    // --- layer 2: 64 -> 64 (in-place)
    {
      float acc[16];
#pragma unroll
      for (int i = 0; i < 16; ++i) acc[i] = 0.0f;
      if (active) {
        const float* xr = &H.x0[lane * 67];
#pragma unroll 2
        for (int c = 0; c < 64; ++c) {
          float xv = xr[c];
          const float4* wr = (const float4*)(W1 + c * 64 + j0);
          float4 wa = wr[0], wb = wr[1], wc = wr[2], wd = wr[3];
          acc[0]  = fmaf(xv, wa.x, acc[0]);  acc[1]  = fmaf(xv, wa.y, acc[1]);
          acc[2]  = fmaf(xv, wa.z, acc[2]);  acc[3]  = fmaf(xv, wa.w, acc[3]);
          acc[4]  = fmaf(xv, wb.x, acc[4]);  acc[5]  = fmaf(xv, wb.y, acc[5]);
          acc[6]  = fmaf(xv, wb.z, acc[6]);  acc[7]  = fmaf(xv, wb.w, acc[7]);
          acc[8]  = fmaf(xv, wc.x, acc[8]);  acc[9]  = fmaf(xv, wc.y, acc[9]);
          acc[10] = fmaf(xv, wc.z, acc[10]); acc[11] = fmaf(xv, wc.w, acc[11]);
          acc[12] = fmaf(xv, wd.x, acc[12]); acc[13] = fmaf(xv, wd.y, acc[13]);
          acc[14] = fmaf(xv, wd.z, acc[14]); acc[15] = fmaf(xv, wd.w, acc[15]);
        }
      }
      __syncthreads();
      if (active) {
#pragma unroll
        for (int i = 0; i < 16; ++i) {
          float y = fmaf(acc[i], C.sAB[128 + j0 + i], C.sAB[192 + j0 + i]);
          H.x0[lane * 67 + j0 + i] = fmaxf(y, 0.0f);
        }
      }
    }
    __syncthreads();
    // --- layer 3: 64 -> 128 + max over 32 rows per centroid
    if (active) {
      const int j3 = __builtin_amdgcn_readfirstlane(hw * 32);
      float acc[32];
#pragma unroll
      for (int i = 0; i < 32; ++i) acc[i] = 0.0f;
      const float* xr = &H.x0[lane * 67];
      for (int c = 0; c < 64; ++c) {
        float xv = xr[c];
        const float4* wr = (const float4*)(W2 + c * 128 + j3);
#pragma unroll
        for (int q = 0; q < 8; ++q) {
          float4 wq = wr[q];
          acc[q * 4 + 0] = fmaf(xv, wq.x, acc[q * 4 + 0]);
          acc[q * 4 + 1] = fmaf(xv, wq.y, acc[q * 4 + 1]);
          acc[q * 4 + 2] = fmaf(xv, wq.z, acc[q * 4 + 2]);
          acc[q * 4 + 3] = fmaf(xv, wq.w, acc[q * 4 + 3]);
        }
      }
#pragma unroll
      for (int i = 0; i < 32; ++i) {
        float y = fmaf(acc[i], C.sAB[256 + j3 + i], C.sAB[384 + j3 + i]);
        u32 mb = __float_as_uint(fmaxf(y, 0.0f));
        HALF_RED_UMAX32(mb);
        acc[i] = __uint_as_float(mb);
      }
      if (lane == 31 || lane == 63) {
        int cent = lane >> 5;
        float4* op = (float4*)(out1 + ((size_t)b * NS + s0 + cent) * 128 + j3);
#pragma unroll
        for (int q = 0; q < 8; ++q)
          op[q] = make_float4(acc[q * 4 + 0], acc[q * 4 + 1], acc[q * 4 + 2], acc[q * 4 + 3]);
      }
    }
  }
}

// ---------------------------------------------------------------- launcher
extern "C" void kernel_launch(void* const* d_in, const int* in_sizes, int n_in,
                              void* d_out, int out_size, void* d_ws, size_t ws_size,
                              hipStream_t stream) {
  const float* xyz = (const float*)d_in[0];
  const float* pts = (const float*)d_in[1];
  const float* W0 = (const float*)d_in[2];  const float* b0 = (const float*)d_in[3];
  const float* g0 = (const float*)d_in[4];  const float* be0 = (const float*)d_in[5];
  const float* m0 = (const float*)d_in[6];  const float* v0 = (const float*)d_in[7];
  const float* W1 = (const float*)d_in[8];  const float* b1 = (const float*)d_in[9];
  const float* g1 = (const float*)d_in[10]; const float* be1 = (const float*)d_in[11];
  const float* m1 = (const float*)d_in[12]; const float* v1 = (const float*)d_in[13];
  const float* W2 = (const float*)d_in[14]; const float* b2 = (const float*)d_in[15];
  const float* g2 = (const float*)d_in[16]; const float* be2 = (const float*)d_in[17];
  const float* m2 = (const float*)d_in[18]; const float* v2 = (const float*)d_in[19];

  float* out0 = (float*)d_out;           // new_xyz    (B,S,3)
  float* out1 = out0 + NB * NS * 3;      // new_points (B,S,128)
  int* prog = (int*)d_ws;                // progress[b] at int b*16 (64B-strided lines)
  int* ctr  = (int*)d_ws + 320;          // work counter, own line

  hipMemsetAsync(d_ws, 0, 2048, stream);

  // Ordinary launch: grid 256 <= residency capacity and producers are blocks
  // 0-15 (dispatched first) -> co-residency safe (R13-verified, saved ~40us).
  fused_kernel<<<256, 512, 0, stream>>>(
      xyz, pts,
      W0, b0, g0, be0, m0, v0,
      W1, b1, g1, be1, m1, v1,
      W2, b2, g2, be2, m2, v2,
      out0, out1, prog, ctr);
}

// Round 15
// 831.256 us; speedup vs baseline: 4.7097x; 4.7097x over previous
//
#include <hip/hip_runtime.h>

// PointNet Set Abstraction (B=16, N=4096, S=1024, K=32, D=64, mlp 67->64->64->128)
// All buffers float32. Exact fp32 (RN, numpy op order) for all DECISIONS.
//
// R15 = exact revert to R13 (known-good 831us). R14's winner-coord publish
// widened the post-barrier live set (~90+ VGPRs) past the allocator's 72-VGPR
// occupancy anchor -> scratch spills (WRITE_SIZE 8.5->127MB, 5x slowdown).
// R13 structure: fused single kernel, ordinary launch grid=256 (coop-launch
// overhead ~40us removed; producers = blocks 0-15 dispatched first, grid <=
// residency capacity -> spin-deadlock impossible). Producer = R5 u64-DPP FPS
// core w/ register-capture + 16-wide burst publish + padded progress lines.
// Consumer = ballot first-K ball query + in-place 3-layer MLP + DPP maxpool.

typedef unsigned int   u32;
typedef unsigned long long u64;

#define NB 16
#define NP 4096
#define NS 1024
#define NK 32
#define NITEM (NB * NS / 2)   // 8192 pair items

#define DPP_UPD(v, ctrl) ((u32)__builtin_amdgcn_update_dpp((int)(v), (int)(v), (ctrl), 0xf, 0xf, false))
#define U64_STEP(v, ctrl) { \
  u32 _lo = DPP_UPD((u32)(v), ctrl); \
  u32 _hi = DPP_UPD((u32)((v) >> 32), ctrl); \
  u64 _o = (((u64)_hi) << 32) | _lo; \
  v = (v > _o) ? v : _o; }
#define WAVE_RED_U64MAX(v) do { U64_STEP(v,0x111); U64_STEP(v,0x112); U64_STEP(v,0x114); \
                                U64_STEP(v,0x118); U64_STEP(v,0x142); U64_STEP(v,0x143); } while (0)
#define UMAX_DPP(v, ctrl) { u32 _o = DPP_UPD(v, ctrl); v = (v > _o) ? v : _o; }
#define HALF_RED_UMAX32(v) do { UMAX_DPP(v,0x111); UMAX_DPP(v,0x112); UMAX_DPP(v,0x114); \
                                UMAX_DPP(v,0x118); UMAX_DPP(v,0x142); } while (0)

struct FpsS { float lx[NP], ly[NP], lz[NP]; u64 red[2][8]; };
struct HalfS {
  float x0[64 * 67];
  u64 masks[2][64];
  int offs[2][64];
  int idx_ls[2][NK];
  float cent[8];
};
struct ConS { HalfS h[2]; float sAB[512]; int shi; };
union SMem { FpsS f; ConS c; };

__device__ __forceinline__ float dload_f(const float* p) {
  return __uint_as_float(__hip_atomic_load((const u32*)p, __ATOMIC_RELAXED, __HIP_MEMORY_SCOPE_AGENT));
}

__global__ void __launch_bounds__(512)
fused_kernel(const float* __restrict__ xyz, const float* __restrict__ pts,
             const float* __restrict__ W0, const float* __restrict__ b0, const float* __restrict__ g0,
             const float* __restrict__ be0, const float* __restrict__ m0, const float* __restrict__ v0,
             const float* __restrict__ W1, const float* __restrict__ b1, const float* __restrict__ g1,
             const float* __restrict__ be1, const float* __restrict__ m1, const float* __restrict__ v1,
             const float* __restrict__ W2, const float* __restrict__ b2, const float* __restrict__ g2,
             const float* __restrict__ be2, const float* __restrict__ m2, const float* __restrict__ v2,
             float* __restrict__ out0, float* __restrict__ out1,
             int* __restrict__ progress, int* __restrict__ ctr)
{
  __shared__ SMem sm;
  const int t = threadIdx.x;

  if (blockIdx.x < NB) {
    // ================= FPS producer (register-capture + burst publish) =================
    asm volatile("s_setprio 3");
    FpsS& S = sm.f;
    const int b = blockIdx.x;
    const int lane = t & 63, wv = t >> 6;
    const float* bx = xyz + (size_t)b * NP * 3;
    for (int i = t; i < NP; i += 512) {
      S.lx[i] = bx[i * 3 + 0];
      S.ly[i] = bx[i * 3 + 1];
      S.lz[i] = bx[i * 3 + 2];
    }
    __syncthreads();

    float px[8], py[8], pz[8], md[8];
#pragma unroll
    for (int p = 0; p < 8; ++p) {
      int i = p * 512 + t;
      px[p] = S.lx[i]; py[p] = S.ly[i]; pz[p] = S.lz[i];
      md[p] = 1e10f;
    }
    const u32 nt = ~(u32)t;
    float cx = S.lx[0], cy = S.ly[0], cz = S.lz[0];
    float hx = cx, hy = cy, hz = cz;   // lane 0's capture slot = centroid 0 (seed)

    for (int it = 1; it < NS; ++it) {
      u32 vb, ca;
      {
        float dx = __fsub_rn(px[0], cx);
        float dy = __fsub_rn(py[0], cy);
        float dz = __fsub_rn(pz[0], cz);
        float d  = __fadd_rn(__fadd_rn(__fmul_rn(dx, dx), __fmul_rn(dy, dy)), __fmul_rn(dz, dz));
        float m2 = fminf(md[0], d);
        md[0] = m2;
        vb = __float_as_uint(m2);
        ca = nt;
      }
#pragma unroll
      for (int p = 1; p < 8; ++p) {
        float dx = __fsub_rn(px[p], cx);
        float dy = __fsub_rn(py[p], cy);
        float dz = __fsub_rn(pz[p], cz);
        float d  = __fadd_rn(__fadd_rn(__fmul_rn(dx, dx), __fmul_rn(dy, dy)), __fmul_rn(dz, dz));
        float m2 = fminf(md[p], d);
        md[p] = m2;
        u32 mb = __float_as_uint(m2);
        bool gt = mb > vb;                      // strict > keeps first idx on ties
        vb = gt ? mb : vb;
        ca = gt ? (nt - (u32)(p * 512)) : ca;   // ~(p*512+t)
      }
      u64 key = (((u64)vb) << 32) | ca;
      WAVE_RED_U64MAX(key);
      const int par = it & 1;
      if (lane == 63) S.red[par][wv] = key;
      __syncthreads();
      u64 k0 = S.red[par][0], k1 = S.red[par][1], k2 = S.red[par][2], k3 = S.red[par][3];
      u64 k4 = S.red[par][4], k5 = S.red[par][5], k6 = S.red[par][6], k7 = S.red[par][7];
      u64 m01 = (k0 > k1) ? k0 : k1;
      u64 m23 = (k2 > k3) ? k2 : k3;
      u64 m45 = (k4 > k5) ? k4 : k5;
      u64 m67 = (k6 > k7) ? k6 : k7;
      u64 ma = (m01 > m23) ? m01 : m23;
      u64 mb = (m45 > m67) ? m45 : m67;
      u64 bk = (ma > mb) ? ma : mb;
      const int idx = (int)(~(u32)bk);
      cx = S.lx[idx]; cy = S.ly[idx]; cz = S.lz[idx];
      if (wv == 0) {
        // lane (it&15) captures this iteration's centroid
        bool cap = (lane == (it & 15));
        hx = cap ? cx : hx;
        hy = cap ? cy : hy;
        hz = cap ? cz : hz;
        if ((it & 15) == 15) {
          if (lane < 16) {                       // burst cents (it-15)..it, 192B coalesced
            float* o = out0 + ((size_t)b * NS + (it - 15) + lane) * 3;
            o[0] = hx; o[1] = hy; o[2] = hz;
          }
          if (lane == 0)                         // release fences the burst agent-wide
            __hip_atomic_store(&progress[b * 16], it + 1, __ATOMIC_RELEASE, __HIP_MEMORY_SCOPE_AGENT);
        }
      }
    }
    return;
  }

  // ================= consumer (byte-identical to R13) =================
  ConS& C = sm.c;
  const int half = t >> 8;
  const int u = t & 255;
  const int lane = t & 63;
  const int hw = u >> 6;
  HalfS& H = C.h[half];
  const float R2 = (float)(0.2 * 0.2);

  if (t < 256) {
    const float *gp, *bep, *mp, *vp, *bpp; int c, base, bcoff;
    if (t < 64)       { c = t;       gp = g0; bep = be0; mp = m0; vp = v0; bpp = b0; base = 0;   bcoff = 64;  }
    else if (t < 128) { c = t - 64;  gp = g1; bep = be1; mp = m1; vp = v1; bpp = b1; base = 128; bcoff = 64;  }
    else              { c = t - 128; gp = g2; bep = be2; mp = m2; vp = v2; bpp = b2; base = 256; bcoff = 128; }
    float a = gp[c] / sqrtf(vp[c] + 1e-5f);
    C.sAB[base + c] = a;
    C.sAB[base + bcoff + c] = (bpp[c] - mp[c]) * a + bep[c];
  }
  __syncthreads();

  for (;;) {
    if (t == 0) C.shi = atomicAdd(ctr, 2);
    __syncthreads();
    const int i0 = C.shi;
    if (i0 >= NITEM) break;
    const int item = i0 + half;
    const bool active = item < NITEM;
    const int b = item & 15, pr = item >> 4, s0 = pr * 2;

    if (u == 0 && active) {
      const int need = s0 + 2;
      while (__hip_atomic_load(&progress[b * 16], __ATOMIC_ACQUIRE, __HIP_MEMORY_SCOPE_AGENT) < need)
        __builtin_amdgcn_s_sleep(32);
      const float* cp = out0 + ((size_t)b * NS + s0) * 3;
#pragma unroll
      for (int i2 = 0; i2 < 6; ++i2) H.cent[i2] = dload_f(cp + i2);
    }
    __syncthreads();
    const float c0x = H.cent[0], c0y = H.cent[1], c0z = H.cent[2];
    const float c1x = H.cent[3], c1y = H.cent[4], c1z = H.cent[5];
    const float* bx = xyz + (size_t)b * NP * 3;

    if (active) {
      for (int c = 0; c < 16; ++c) {
        int ch = hw * 16 + c;
        int i = ch * 64 + lane;
        float X = bx[i * 3 + 0], Y = bx[i * 3 + 1], Z = bx[i * 3 + 2];
        float dx0 = __fsub_rn(c0x, X), dy0 = __fsub_rn(c0y, Y), dz0 = __fsub_rn(c0z, Z);
        float d20 = __fadd_rn(__fadd_rn(__fmul_rn(dx0, dx0), __fmul_rn(dy0, dy0)), __fmul_rn(dz0, dz0));
        u64 mA = __ballot(d20 < R2);
        float dx1 = __fsub_rn(c1x, X), dy1 = __fsub_rn(c1y, Y), dz1 = __fsub_rn(c1z, Z);
        float d21 = __fadd_rn(__fadd_rn(__fmul_rn(dx1, dx1), __fmul_rn(dy1, dy1)), __fmul_rn(dz1, dz1));
        u64 mB = __ballot(d21 < R2);
        if (lane == 0) { H.masks[0][ch] = mA; H.masks[1][ch] = mB; }
      }
      if (u < 64) H.idx_ls[u >> 5][u & 31] = -1;
    }
    __syncthreads();
    if (active && (hw & 1) == 0) {
      int cent = hw >> 1;
      int cnt = __popcll(H.masks[cent][lane]);
      int inc = cnt;
#pragma unroll
      for (int off = 1; off < 64; off <<= 1) {
        int n = __shfl_up(inc, off);
        if (lane >= off) inc += n;
      }
      H.offs[cent][lane] = inc - cnt;
    }
    __syncthreads();
    if (active) {
      for (int c = 0; c < 16; ++c) {
        int ch = hw * 16 + c;
#pragma unroll
        for (int cent = 0; cent < 2; ++cent) {
          int base = H.offs[cent][ch];
          if (base >= NK) continue;
          u64 m = H.masks[cent][ch];
          if ((m >> lane) & 1ull) {
            int slot = base + __popcll(m & ((1ull << lane) - 1ull));
            if (slot < NK) H.idx_ls[cent][slot] = ch * 64 + lane;
          }
        }
      }
    }
    __syncthreads();
    if (active) {
      int cent = u >> 7, tt = u & 127;
      int row = tt >> 2, q = tt & 3;
      int id = H.idx_ls[cent][row];
      int prow = (id < 0) ? (NP - 1) : id;          // torch -1 wrap
      const float4* p4 = (const float4*)(pts + ((size_t)b * NP + prow) * 64 + q * 16);
      float4 va = p4[0], vb = p4[1], vc = p4[2], vd = p4[3];
      float* dst = &H.x0[(cent * 32 + row) * 67 + 3 + q * 16];
      dst[0]  = va.x; dst[1]  = va.y; dst[2]  = va.z; dst[3]  = va.w;
      dst[4]  = vb.x; dst[5]  = vb.y; dst[6]  = vb.z; dst[7]  = vb.w;
      dst[8]  = vc.x; dst[9]  = vc.y; dst[10] = vc.z; dst[11] = vc.w;
      dst[12] = vd.x; dst[13] = vd.y; dst[14] = vd.z; dst[15] = vd.w;
      if (u < 64) {
        int c2 = u >> 5, slot = u & 31;
        int id2 = H.idx_ls[c2][slot];
        float ax = c2 ? c1x : c0x, ay = c2 ? c1y : c0y, az = c2 ? c1z : c0z;
        float gx, gy, gz;
        if (id2 >= 0) {
          gx = __fsub_rn(bx[id2 * 3 + 0], ax);
          gy = __fsub_rn(bx[id2 * 3 + 1], ay);
          gz = __fsub_rn(bx[id2 * 3 + 2], az);
        } else {
          gx = 0.0f - ax; gy = 0.0f - ay; gz = 0.0f - az;
        }
        float* d2p = &H.x0[(c2 * 32 + slot) * 67];
        d2p[0] = gx; d2p[1] = gy; d2p[2] = gz;
      }
    }
    __syncthreads();

    const int j0 = __builtin_amdgcn_readfirstlane(hw * 16);
    // --- layer 1: 67 -> 64 (in-place)
    {
      float acc[16];
#pragma unroll
      for (int i = 0; i < 16; ++i) acc[i] = 0.0f;
      if (active) {
        const float* xr = &H.x0[lane * 67];
#pragma unroll 2
        for (int c = 0; c < 67; ++c) {
          float xv = xr[c];
          const float4* wr = (const float4*)(W0 + c * 64 + j0);
          float4 wa = wr[0], wb = wr[1], wc = wr[2], wd = wr[3];
          acc[0]  = fmaf(xv, wa.x, acc[0]);  acc[1]  = fmaf(xv, wa.y, acc[1]);
          acc[2]  = fmaf(xv, wa.z, acc[2]);  acc[3]  = fmaf(xv, wa.w, acc[3]);
          acc[4]  = fmaf(xv, wb.x, acc[4]);  acc[5]  = fmaf(xv, wb.y, acc[5]);
          acc[6]  = fmaf(xv, wb.z, acc[6]);  acc[7]  = fmaf(xv, wb.w, acc[7]);
          acc[8]  = fmaf(xv, wc.x, acc[8]);  acc[9]  = fmaf(xv, wc.y, acc[9]);
          acc[10] = fmaf(xv, wc.z, acc[10]); acc[11] = fmaf(xv, wc.w, acc[11]);
          acc[12] = fmaf(xv, wd.x, acc[12]); acc[13] = fmaf(xv, wd.y, acc[13]);
          acc[14] = fmaf(xv, wd.z, acc[14]); acc[15] = fmaf(xv, wd.w, acc[15]);
        }
      }
      __syncthreads();
      if (active) {
#pragma unroll
        for (int i = 0; i < 16; ++i) {
          float y = fmaf(acc[i], C.sAB[j0 + i], C.sAB[64 + j0 + i]);
          H.x0[lane * 67 + j0 + i] = fmaxf(y, 0.0f);
        }
      }
    }
    __syncthreads();
    // --- layer 2: 64 -> 64 (in-place)
    {
      float acc[16];
#pragma unroll
      for (int i = 0; i < 16; ++i) acc[i] = 0.0f;
      if (active) {
        const float* xr = &H.x0[lane * 67];
#pragma unroll 2
        for (int c = 0; c < 64; ++c) {
          float xv = xr[c];
          const float4* wr = (const float4*)(W1 + c * 64 + j0);
          float4 wa = wr[0], wb = wr[1], wc = wr[2], wd = wr[3];
          acc[0]  = fmaf(xv, wa.x, acc[0]);  acc[1]  = fmaf(xv, wa.y, acc[1]);
          acc[2]  = fmaf(xv, wa.z, acc[2]);  acc[3]  = fmaf(xv, wa.w, acc[3]);
          acc[4]  = fmaf(xv, wb.x, acc[4]);  acc[5]  = fmaf(xv, wb.y, acc[5]);
          acc[6]  = fmaf(xv, wb.z, acc[6]);  acc[7]  = fmaf(xv, wb.w, acc[7]);
          acc[8]  = fmaf(xv, wc.x, acc[8]);  acc[9]  = fmaf(xv, wc.y, acc[9]);
          acc[10] = fmaf(xv, wc.z, acc[10]); acc[11] = fmaf(xv, wc.w, acc[11]);
          acc[12] = fmaf(xv, wd.x, acc[12]); acc[13] = fmaf(xv, wd.y, acc[13]);
          acc[14] = fmaf(xv, wd.z, acc[14]); acc[15] = fmaf(xv, wd.w, acc[15]);
        }
      }
      __syncthreads();
      if (active) {
#pragma unroll
        for (int i = 0; i < 16; ++i) {
          float y = fmaf(acc[i], C.sAB[128 + j0 + i], C.sAB[192 + j0 + i]);
          H.x0[lane * 67 + j0 + i] = fmaxf(y, 0.0f);
        }
      }
    }
    __syncthreads();
    // --- layer 3: 64 -> 128 + max over 32 rows per centroid
    if (active) {
      const int j3 = __builtin_amdgcn_readfirstlane(hw * 32);
      float acc[32];
#pragma unroll
      for (int i = 0; i < 32; ++i) acc[i] = 0.0f;
      const float* xr = &H.x0[lane * 67];
      for (int c = 0; c < 64; ++c) {
        float xv = xr[c];
        const float4* wr = (const float4*)(W2 + c * 128 + j3);
#pragma unroll
        for (int q = 0; q < 8; ++q) {
          float4 wq = wr[q];
          acc[q * 4 + 0] = fmaf(xv, wq.x, acc[q * 4 + 0]);
          acc[q * 4 + 1] = fmaf(xv, wq.y, acc[q * 4 + 1]);
          acc[q * 4 + 2] = fmaf(xv, wq.z, acc[q * 4 + 2]);
          acc[q * 4 + 3] = fmaf(xv, wq.w, acc[q * 4 + 3]);
        }
      }
#pragma unroll
      for (int i = 0; i < 32; ++i) {
        float y = fmaf(acc[i], C.sAB[256 + j3 + i], C.sAB[384 + j3 + i]);
        u32 mb = __float_as_uint(fmaxf(y, 0.0f));
        HALF_RED_UMAX32(mb);
        acc[i] = __uint_as_float(mb);
      }
      if (lane == 31 || lane == 63) {
        int cent = lane >> 5;
        float4* op = (float4*)(out1 + ((size_t)b * NS + s0 + cent) * 128 + j3);
#pragma unroll
        for (int q = 0; q < 8; ++q)
          op[q] = make_float4(acc[q * 4 + 0], acc[q * 4 + 1], acc[q * 4 + 2], acc[q * 4 + 3]);
      }
    }
  }
}

// ---------------------------------------------------------------- launcher
extern "C" void kernel_launch(void* const* d_in, const int* in_sizes, int n_in,
                              void* d_out, int out_size, void* d_ws, size_t ws_size,
                              hipStream_t stream) {
  const float* xyz = (const float*)d_in[0];
  const float* pts = (const float*)d_in[1];
  const float* W0 = (const float*)d_in[2];  const float* b0 = (const float*)d_in[3];
  const float* g0 = (const float*)d_in[4];  const float* be0 = (const float*)d_in[5];
  const float* m0 = (const float*)d_in[6];  const float* v0 = (const float*)d_in[7];
  const float* W1 = (const float*)d_in[8];  const float* b1 = (const float*)d_in[9];
  const float* g1 = (const float*)d_in[10]; const float* be1 = (const float*)d_in[11];
  const float* m1 = (const float*)d_in[12]; const float* v1 = (const float*)d_in[13];
  const float* W2 = (const float*)d_in[14]; const float* b2 = (const float*)d_in[15];
  const float* g2 = (const float*)d_in[16]; const float* be2 = (const float*)d_in[17];
  const float* m2 = (const float*)d_in[18]; const float* v2 = (const float*)d_in[19];

  float* out0 = (float*)d_out;           // new_xyz    (B,S,3)
  float* out1 = out0 + NB * NS * 3;      // new_points (B,S,128)
  int* prog = (int*)d_ws;                // progress[b] at int b*16 (64B-strided lines)
  int* ctr  = (int*)d_ws + 320;          // work counter, own line

  hipMemsetAsync(d_ws, 0, 2048, stream);

  // Ordinary launch: grid 256 <= residency capacity and producers are blocks
  // 0-15 (dispatched first) -> co-residency safe (R13-verified, saved ~40us).
  fused_kernel<<<256, 512, 0, stream>>>(
      xyz, pts,
      W0, b0, g0, be0, m0, v0,
      W1, b1, g1, be1, m1, v1,
      W2, b2, g2, be2, m2, v2,
      out0, out1, prog, ctr);
}